// Round 13
// baseline (281.240 us; speedup 1.0000x reference)
//
#include <hip/hip_runtime.h>

// LSTM: B=2048, T=512, D=1, H=50, OUT=3, fp32.
//
// R14 = R12 (NW=16, K-aug, prescale) + R13 (conflict-free frag-order LDS).
// History (dispatch us):
//  R1-R4 582..539 VALU-bound; R5 381; R6 291 (NW13); R7 345 (NW8); R8
//  268.6 (fp16 2-term); R9 269 (null); R10 316 (NW4); R11 FAIL (clobber);
//  R12 214.5 (K-aug + prescale + NW16); R13 233 (frag-order layout proved
//  conflicts 1.03e7->1.86e6, but NW=8 lost more than layout won).
// Established: wave-count ranking NW16 > NW13 > NW8 > NW4 (occupancy
// hides ds_read latency + update chains); frag-order layout kills read
// conflicts. R14 combines the proven halves (pre-declared fallback).
//
// Structure (all R5-R13 verified conventions):
//  * NW=16 waves, 1 tile each; unit = 4w+hi; 4 waves/SIMD balanced.
//  * h/aug in frag-order: elem (k,b) at u16 idx 128*(k>>3)+8*b+(k&7).
//    Read: B0 = bytes 16*lane of 1KB region, B1 at +512 u16 (conflict-
//    free). Write: u=4w+hi -> idx 128*(w>>1)+8*bcol+4*(w&1)+hi, 1 b16,
//    guarded u<50. Aug (k=61,62,63 -> idx 896+8b+{5,6,7}) by wave 15
//    (all-pad): slot62=1.0, 63=x_hi, 61=x_lo' (x = xh + 2^-11 xl').
//  * K-augmentation: bias/x fold into MFMA via aug slots; acc starts
//    from persistent zero4; L-prescale (-log2e / -2log2e) in A hi/lo;
//    merged-rcp cell (R9 algebra); fp16 2-term W; fp16 h; 1 barrier/step.

#define BB 2048
#define TT 512
#define HH 50
#define NB 16            // batches per block (= MFMA cols)
#define NW 16            // waves = tiles; 64 unit slots (50 real)
#define XP 513           // xs row stride (floats)
#define LO_SCALE  2048.0f            // 2^11
#define LO_ISCALE 0.00048828125f     // 2^-11
#define L1 -1.4426950408889634f      // -log2(e)
#define L2 -2.8853900817779268f      // -2*log2(e)

typedef __attribute__((ext_vector_type(4))) float    f32x4;
typedef __attribute__((ext_vector_type(8))) _Float16 f16x8;

#define F16BITS(v) __builtin_bit_cast(unsigned short, (_Float16)(v))

__global__ __launch_bounds__(NW * 64)
void lstm_r14_kernel(const float* __restrict__ x,
                     const float* __restrict__ W_ih,
                     const float* __restrict__ W_hh,
                     const float* __restrict__ b_ih,
                     const float* __restrict__ b_hh,
                     const float* __restrict__ fc_w,
                     const float* __restrict__ fc_b,
                     float* __restrict__ out) {
    __shared__ float xs[NB * XP];                         // 32.8 KB
    __shared__ __align__(16) unsigned short hb[2][1024];  // 4 KB, frag-order
    __shared__ float hfin[NB][64];                        // 4 KB

    const int tid  = threadIdx.x;
    const int w    = tid >> 6;          // wave id = tile id, 0..15
    const int lane = tid & 63;
    const int hi   = lane >> 4;
    const int bcol = lane & 15;         // batch column
    const int b0   = blockIdx.x * NB;

    // ---- stage x rows (coalesced) + zero pad col 512 ----
    for (int idx = tid; idx < NB * TT; idx += NW * 64) {
        xs[(idx >> 9) * XP + (idx & 511)] = x[(b0 + (idx >> 9)) * TT + (idx & 511)];
    }
    if (tid < NB) xs[tid * XP + 512] = 0.0f;
    // ---- zero h buffers (both; pad slots stay 0 forever) ----
    for (int idx = tid; idx < (int)(sizeof(hb) / 4); idx += NW * 64) {
        ((unsigned*)hb)[idx] = 0;
    }

    // ---- A-fragments: permuted rows, L-prescaled fp16 hi/lo, augmented ----
    // Lane supplies A row R = lane&15: gate ga = R&3, unit ua = 4w+(R>>2).
    // k cols: [0,50)=Lg*W_hh hi/lo; 61: Al=Lg*W_ih (pairs x_lo'); 62: bias
    // hi/lo (pairs 1.0); 63: Lg*W_ih hi/lo (pairs x_hi).
    const int ga = bcol & 3;
    const int ua = 4 * w + (bcol >> 2);
    const bool ok = (ua < HH);
    const float Lg = (ga == 2) ? L2 : L1;
    f16x8 Ah0, Ah1, Al0, Al1;
    #pragma unroll
    for (int s = 0; s < 2; ++s) {
        #pragma unroll
        for (int e = 0; e < 8; ++e) {
            const int k = 32 * s + 8 * hi + e;
            _Float16 ah = (_Float16)0.0f, al = (_Float16)0.0f;
            if (ok) {
                if (k < HH) {
                    const float wv = Lg * W_hh[(ga * HH + ua) * HH + k];
                    ah = (_Float16)wv;
                    al = (_Float16)((wv - (float)ah) * LO_SCALE);
                } else if (k == 61) {
                    al = (_Float16)(Lg * W_ih[ga * HH + ua]);
                } else if (k == 62) {
                    const float bv = Lg * (b_ih[ga * HH + ua] + b_hh[ga * HH + ua]);
                    ah = (_Float16)bv;
                    al = (_Float16)((bv - (float)ah) * LO_SCALE);
                } else if (k == 63) {
                    const float wv = Lg * W_ih[ga * HH + ua];
                    ah = (_Float16)wv;
                    al = (_Float16)((wv - (float)ah) * LO_SCALE);
                }
            }
            if (s == 0) { Ah0[e] = ah; Al0[e] = al; }
            else        { Ah1[e] = ah; Al1[e] = al; }
        }
    }

    // ---- LDS pointers (u16 units; buffer = 1024 u16) ----
    // Read: lane's B0 at u16 idx 8*lane (bytes 16*lane); B1 at +512.
    const unsigned short* rbase = &hb[0][0] + 8 * lane;
    // Write: unit u=4w+hi, batch bcol -> 128*(w>>1) + 8*bcol + 4*(w&1) + hi.
    unsigned short* wb = &hb[0][0] + 128 * (w >> 1) + 8 * bcol + 4 * (w & 1) + hi;
    const bool hwriter = (4 * w + hi) < HH;
    // Aug (k=61,62,63): idx 896 + 8*b + {5,6,7}. Wave 15 (all-pad) writes.
    const bool xwriter = (w == 15) && (hi == 3);
    unsigned short* xwb = &hb[0][0] + 896 + 8 * bcol;
    const unsigned short one_us = F16BITS(1.0f);

    __syncthreads();   // staging + zero-init complete

    // ---- prologue: buf0 aug = (x_lo'(0), 1.0, x_hi(0)) ----
    if (xwriter) {
        const float x0 = xs[bcol * XP + 0];
        const _Float16 xh = (_Float16)x0;
        const _Float16 xl = (_Float16)((x0 - (float)xh) * LO_SCALE);
        *(unsigned*)(xwb + 6) =
            (unsigned)one_us | ((unsigned)__builtin_bit_cast(unsigned short, xh) << 16);
        xwb[5] = __builtin_bit_cast(unsigned short, xl);
    }

    float c = 0.0f, hcur = 0.0f;
    const f32x4 zero4 = {0.0f, 0.0f, 0.0f, 0.0f};

    __syncthreads();

    // One step: read buf CB (h(t-1) + aug x(t)), write buf 1-CB, one barrier.
#define STEP(CB, T) { \
        const f16x8 B0 = *(const f16x8*)(rbase + (CB) * 1024); \
        const f16x8 B1 = *(const f16x8*)(rbase + (CB) * 1024 + 512); \
        f32x4 acc  = __builtin_amdgcn_mfma_f32_16x16x32_f16(Ah0, B0, zero4, 0, 0, 0); \
        f32x4 acc2 = __builtin_amdgcn_mfma_f32_16x16x32_f16(Al0, B0, zero4, 0, 0, 0); \
        acc  = __builtin_amdgcn_mfma_f32_16x16x32_f16(Ah1, B1, acc,  0, 0, 0); \
        acc2 = __builtin_amdgcn_mfma_f32_16x16x32_f16(Al1, B1, acc2, 0, 0, 0); \
        const float v0 = fmaf(acc2[0], LO_ISCALE, acc[0]); \
        const float v1 = fmaf(acc2[1], LO_ISCALE, acc[1]); \
        const float v2 = fmaf(acc2[2], LO_ISCALE, acc[2]); \
        const float v3 = fmaf(acc2[3], LO_ISCALE, acc[3]); \
        const float E1 = __builtin_amdgcn_exp2f(v0);   /* i */ \
        const float E2 = __builtin_amdgcn_exp2f(v1);   /* f */ \
        const float G  = __builtin_amdgcn_exp2f(v2);   /* g */ \
        const float E4 = __builtin_amdgcn_exp2f(v3);   /* o */ \
        const float P1 = 1.0f + E1, P2 = 1.0f + E2; \
        const float PG = 1.0f + G,  P4 = 1.0f + E4; \
        const float MG = 1.0f - G; \
        const float N  = fmaf(c * P1, PG, MG * P2); \
        const float D  = (P1 * P2) * PG; \
        c = N * __builtin_amdgcn_rcpf(D); \
        const float C5 = __builtin_amdgcn_exp2f(L2 * c); \
        const float Q  = (1.0f + C5) * P4; \
        hcur = (1.0f - C5) * __builtin_amdgcn_rcpf(Q); \
        if (hwriter) wb[(1 - (CB)) * 1024] = F16BITS(hcur); \
        if (xwriter) { \
            const float xn = xs[bcol * XP + (T) + 1]; \
            const _Float16 xh = (_Float16)xn; \
            const _Float16 xl = (_Float16)((xn - (float)xh) * LO_SCALE); \
            *(unsigned*)(xwb + (1 - (CB)) * 1024 + 6) = \
                (unsigned)one_us | ((unsigned)__builtin_bit_cast(unsigned short, xh) << 16); \
            xwb[(1 - (CB)) * 1024 + 5] = __builtin_bit_cast(unsigned short, xl); \
        } \
        __syncthreads(); }

    #pragma unroll 1
    for (int t = 0; t < TT; t += 2) {
        STEP(0, t)
        STEP(1, t + 1)
    }
#undef STEP

    // ---- epilogue: h_T dot fc_w (once) ----
    hfin[bcol][4 * w + hi] = hcur;      // pad units hold exact 0
    __syncthreads();
    if (tid < NB * 3) {
        const int b = tid / 3, o = tid % 3;
        float s = fc_b[o];
        for (int uu = 0; uu < HH; ++uu)
            s = fmaf(hfin[b][uu], fc_w[o * HH + uu], s);
        out[(b0 + b) * 3 + o] = s;
    }
}

extern "C" void kernel_launch(void* const* d_in, const int* in_sizes, int n_in,
                              void* d_out, int out_size, void* d_ws, size_t ws_size,
                              hipStream_t stream) {
    const float* x    = (const float*)d_in[0];
    const float* W_ih = (const float*)d_in[1];
    const float* W_hh = (const float*)d_in[2];
    const float* b_ih = (const float*)d_in[3];
    const float* b_hh = (const float*)d_in[4];
    const float* fc_w = (const float*)d_in[5];
    const float* fc_b = (const float*)d_in[6];
    float* out = (float*)d_out;

    dim3 grid(BB / NB);      // 128 blocks
    dim3 block(NW * 64);     // 1024 threads = 16 waves (4 per SIMD)
    lstm_r14_kernel<<<grid, block, 0, stream>>>(x, W_ih, W_hh, b_ih, b_hh,
                                                fc_w, fc_b, out);
}

// Round 14
// 276.893 us; speedup vs baseline: 1.0157x; 1.0157x over previous
//
#include <hip/hip_runtime.h>

// LSTM: B=2048, T=512, D=1, H=50, OUT=3, fp32.
//
// R15 = exact R12 resubmission (best verified: 214.5us dispatch, absmax
// 4.88e-4). History (dispatch us):
//  R1-R4 582..539 VALU-bound lane=unit; R5 381; R6 291 (NW13 fused);
//  R7 345 (NW8); R8 268.6 (fp16 2-term); R9 269 (trim null); R10 316
//  (NW4 latency-exposed); R11 FAIL (aug clobber); R12 214.5 (K-aug +
//  prescale + NW16 balance); R13 233 (frag-order layout: conflicts
//  1.03e7->1.86e6 proven, NW8 cost more); R14 230 (frag-order @ NW16:
//  conflict removal NULL -> LDS was never the critical path at NW16).
//
// Ceiling evidence: step ~1000 cyc with VALU 31%, MFMA 13%, LDS <60% --
// all pipes sub-saturated; time is the serial chain (h-write drain ->
// barrier -> read latency+burst -> MFMA -> update chain) x 512 steps,
// phase-locked across 16 waves. All structural axes measured: NW
// {4,8,13,16}->16 best; layout {strided,frag-order}->strided; precision
// {bf16 3-term, fp16 2-term}->fp16; K-aug -20%; update algebra null;
// masking null. Single-wave barrier-free and antiphase dual-group both
// bound >= ~1000 cyc/step by issue math. This is the practical floor.
//
// Structure (R5-R12 verified conventions):
//  * NW=16 waves, 1 tile each; unit = 4w+hi; 4 waves/SIMD balanced.
//  * h state hf[2][NB][HS=72] u16 fp16, 144B rows, double-buffered;
//    B-frag reads at &hf[buf][bcol][8*hi] (+32 for K-half 2).
//  * K-augmentation: B1 pad slots carry slot62=1.0 (bias hi/lo in A),
//    slot63=x_hi, slot61=x_lo' (x = xh + 2^-11 xl'); wave15 (all-pad)
//    writes them; h-writes guarded to units < 50 (R11 lesson).
//  * L-prescale (-log2e / -2log2e) folded into A hi/lo -> E=exp2(v).
//  * fp16 2-term W (hi + 2^-11*lo RTN); fp16 h; merged-rcp cell (R9);
//    acc starts from persistent zero4; ONE barrier per step.
//  A: row=lane&15 (permuted gate=R&3, unit=4w+(R>>2)), k=8*(lane>>4)+e
//  (+32/K-step); B: col=lane&15, same k; D: col=lane&15, row=4*hi+reg.

#define BB 2048
#define TT 512
#define HH 50
#define NB 16            // batches per block (= MFMA cols)
#define NW 16            // waves = tiles; 64 unit slots (50 real)
#define XP 513           // xs row stride (floats)
#define HS 72            // hf unit-slot stride per batch row (u16; 144B)
#define LO_SCALE  2048.0f            // 2^11
#define LO_ISCALE 0.00048828125f     // 2^-11
#define L1 -1.4426950408889634f      // -log2(e)
#define L2 -2.8853900817779268f      // -2*log2(e)

typedef __attribute__((ext_vector_type(4))) float    f32x4;
typedef __attribute__((ext_vector_type(8))) _Float16 f16x8;

__global__ __launch_bounds__(NW * 64)
void lstm_r15_kernel(const float* __restrict__ x,
                     const float* __restrict__ W_ih,
                     const float* __restrict__ W_hh,
                     const float* __restrict__ b_ih,
                     const float* __restrict__ b_hh,
                     const float* __restrict__ fc_w,
                     const float* __restrict__ fc_b,
                     float* __restrict__ out) {
    __shared__ float xs[NB * XP];                           // 32.8 KB
    __shared__ __align__(16) unsigned short hf[2][NB][HS];  // 4.6 KB (fp16 h + aug)
    __shared__ float hfin[NB][64];                          // 4 KB

    const int tid  = threadIdx.x;
    const int w    = tid >> 6;          // wave id = tile id, 0..15
    const int lane = tid & 63;
    const int hi   = lane >> 4;
    const int bcol = lane & 15;         // batch column
    const int b0   = blockIdx.x * NB;

    // ---- stage x rows (coalesced) + zero pad col 512 ----
    for (int idx = tid; idx < NB * TT; idx += NW * 64) {
        xs[(idx >> 9) * XP + (idx & 511)] = x[(b0 + (idx >> 9)) * TT + (idx & 511)];
    }
    if (tid < NB) xs[tid * XP + 512] = 0.0f;
    // ---- zero h state (both buffers incl. all pad/aug slots) ----
    for (int idx = tid; idx < (int)(sizeof(hf) / 4); idx += NW * 64) {
        ((unsigned*)hf)[idx] = 0;
    }

    // ---- A-fragments: permuted rows, L-prescaled fp16 hi/lo, augmented ----
    // Lane supplies A row R = lane&15: gate ga = R&3, unit ua = 4w+(R>>2).
    // k cols: [0,50)=Lg*W_hh hi/lo; 61: Al=Lg*W_ih (pairs x_lo'); 62: bias
    // hi/lo (pairs 1.0); 63: Lg*W_ih hi/lo (pairs x_hi).
    const int ga = bcol & 3;
    const int ua = 4 * w + (bcol >> 2);
    const bool ok = (ua < HH);
    const float Lg = (ga == 2) ? L2 : L1;
    f16x8 Ah0, Ah1, Al0, Al1;
    #pragma unroll
    for (int s = 0; s < 2; ++s) {
        #pragma unroll
        for (int e = 0; e < 8; ++e) {
            const int k = 32 * s + 8 * hi + e;
            _Float16 ah = (_Float16)0.0f, al = (_Float16)0.0f;
            if (ok) {
                if (k < HH) {
                    const float wv = Lg * W_hh[(ga * HH + ua) * HH + k];
                    ah = (_Float16)wv;
                    al = (_Float16)((wv - (float)ah) * LO_SCALE);
                } else if (k == 61) {
                    al = (_Float16)(Lg * W_ih[ga * HH + ua]);
                } else if (k == 62) {
                    const float bv = Lg * (b_ih[ga * HH + ua] + b_hh[ga * HH + ua]);
                    ah = (_Float16)bv;
                    al = (_Float16)((bv - (float)ah) * LO_SCALE);
                } else if (k == 63) {
                    const float wv = Lg * W_ih[ga * HH + ua];
                    ah = (_Float16)wv;
                    al = (_Float16)((wv - (float)ah) * LO_SCALE);
                }
            }
            if (s == 0) { Ah0[e] = ah; Al0[e] = al; }
            else        { Ah1[e] = ah; Al1[e] = al; }
        }
    }

    // ---- LDS pointers (u16 units). buf stride = NB*HS = 1152 ----
    const unsigned short* rb  = &hf[0][bcol][8 * hi];    // B-frag reads
    unsigned short*       wb  = &hf[0][bcol][4 * w + hi];// h write (unit slot)
    unsigned short*       xwb = &hf[0][bcol][0];         // aug writes
    const bool xwriter = (w == 15) && (hi == 3);
    const bool hwriter = (4 * w + hi) < HH;   // pad units must not write
                                              // (slots 50..63 incl. aug)

    __syncthreads();   // zero-init complete

    // ---- prologue aug writes: 1.0 -> slot62 (both bufs); x(0) -> buf0 ----
    if (xwriter) {
        const unsigned short one_h = __builtin_bit_cast(unsigned short, (_Float16)1.0f);
        xwb[62] = one_h;
        xwb[1152 + 62] = one_h;
        const float x0 = xs[bcol * XP + 0];
        const _Float16 xh = (_Float16)x0;
        const _Float16 xl = (_Float16)((x0 - (float)xh) * LO_SCALE);
        xwb[63] = __builtin_bit_cast(unsigned short, xh);
        xwb[61] = __builtin_bit_cast(unsigned short, xl);
    }

    float c = 0.0f, hcur = 0.0f;
    const f32x4 zero4 = {0.0f, 0.0f, 0.0f, 0.0f};

    __syncthreads();

    // One step: read buf CB (h(t-1) + aug x(t)), write buf 1-CB, one barrier.
#define STEP(CB, T) { \
        const f16x8 B0 = *(const f16x8*)(rb + (CB) * 1152); \
        const f16x8 B1 = *(const f16x8*)(rb + (CB) * 1152 + 32); \
        f32x4 acc  = __builtin_amdgcn_mfma_f32_16x16x32_f16(Ah0, B0, zero4, 0, 0, 0); \
        f32x4 acc2 = __builtin_amdgcn_mfma_f32_16x16x32_f16(Al0, B0, zero4, 0, 0, 0); \
        acc  = __builtin_amdgcn_mfma_f32_16x16x32_f16(Ah1, B1, acc,  0, 0, 0); \
        acc2 = __builtin_amdgcn_mfma_f32_16x16x32_f16(Al1, B1, acc2, 0, 0, 0); \
        /* v = L*preact directly (prescaled rows) */ \
        const float v0 = fmaf(acc2[0], LO_ISCALE, acc[0]); \
        const float v1 = fmaf(acc2[1], LO_ISCALE, acc[1]); \
        const float v2 = fmaf(acc2[2], LO_ISCALE, acc[2]); \
        const float v3 = fmaf(acc2[3], LO_ISCALE, acc[3]); \
        const float E1 = __builtin_amdgcn_exp2f(v0);   /* i */ \
        const float E2 = __builtin_amdgcn_exp2f(v1);   /* f */ \
        const float G  = __builtin_amdgcn_exp2f(v2);   /* g */ \
        const float E4 = __builtin_amdgcn_exp2f(v3);   /* o */ \
        const float P1 = 1.0f + E1, P2 = 1.0f + E2; \
        const float PG = 1.0f + G,  P4 = 1.0f + E4; \
        const float MG = 1.0f - G; \
        const float N  = fmaf(c * P1, PG, MG * P2); \
        const float D  = (P1 * P2) * PG; \
        c = N * __builtin_amdgcn_rcpf(D); \
        const float C5 = __builtin_amdgcn_exp2f(L2 * c); \
        const float Q  = (1.0f + C5) * P4; \
        hcur = (1.0f - C5) * __builtin_amdgcn_rcpf(Q); \
        if (hwriter) \
            wb[(1 - (CB)) * 1152] = __builtin_bit_cast(unsigned short, (_Float16)hcur); \
        if (xwriter) { \
            const float xn = xs[bcol * XP + (T) + 1]; \
            const _Float16 xh = (_Float16)xn; \
            const _Float16 xl = (_Float16)((xn - (float)xh) * LO_SCALE); \
            xwb[(1 - (CB)) * 1152 + 63] = __builtin_bit_cast(unsigned short, xh); \
            xwb[(1 - (CB)) * 1152 + 61] = __builtin_bit_cast(unsigned short, xl); \
        } \
        __syncthreads(); }

    #pragma unroll 1
    for (int t = 0; t < TT; t += 2) {
        STEP(0, t)
        STEP(1, t + 1)
    }
#undef STEP

    // ---- epilogue: h_T dot fc_w (once) ----
    hfin[bcol][4 * w + hi] = hcur;      // pad units hold exact 0
    __syncthreads();
    if (tid < NB * 3) {
        const int b = tid / 3, o = tid % 3;
        float s = fc_b[o];
        for (int uu = 0; uu < HH; ++uu)
            s = fmaf(hfin[b][uu], fc_w[o * HH + uu], s);
        out[(b0 + b) * 3 + o] = s;
    }
}

extern "C" void kernel_launch(void* const* d_in, const int* in_sizes, int n_in,
                              void* d_out, int out_size, void* d_ws, size_t ws_size,
                              hipStream_t stream) {
    const float* x    = (const float*)d_in[0];
    const float* W_ih = (const float*)d_in[1];
    const float* W_hh = (const float*)d_in[2];
    const float* b_ih = (const float*)d_in[3];
    const float* b_hh = (const float*)d_in[4];
    const float* fc_w = (const float*)d_in[5];
    const float* fc_b = (const float*)d_in[6];
    float* out = (float*)d_out;

    dim3 grid(BB / NB);      // 128 blocks
    dim3 block(NW * 64);     // 1024 threads = 16 waves (4 per SIMD)
    lstm_r15_kernel<<<grid, block, 0, stream>>>(x, W_ih, W_hh, b_ih, b_hh,
                                                fc_w, fc_b, out);
}

// Round 15
// 261.960 us; speedup vs baseline: 1.0736x; 1.0570x over previous
//
#include <hip/hip_runtime.h>

// LSTM: B=2048, T=512, D=1, H=50, OUT=3, fp32.
//
// R16: single-term fp16 W_hh + fp32 bias via MFMA C-operand. History
// (dispatch us): R1-R4 582..539; R5 381; R6 291; R7 345; R8 268.6;
// R9 269 (null); R10 316; R11 FAIL; R12 214.5 (K-aug+prescale+NW16);
// R13 233; R14 230 (conflict removal null); R15 228 = R12 source
// (session noise +-6-7% calibrated).
// Step ~950cyc, no pipe saturated: serial chain (~400) + straggler-SIMD
// issue stacking (4 waves x ~45 instr x 2cyc). R16 attacks stacking:
//  * W_hh single-term fp16 RTN (drop lo): MFMA 4->2, combine fmafs ->0
//    (exp2 consumes acc[r] directly). Error: +W-quant 2^-12 indep of
//    h-quant -> predicted absmax ~1e-3 < 2.43e-3 threshold.
//  * bias as MFMA C-operand: loop-invariant f32x4 reg, EXACT fp32 add,
//    zero per-step VALU (better than R12's fp16-pair slots).
//  * x stays 2-term, rebalanced scale XSC=32 (A weight Lg*W_ih/32 and
//    B (x-xh)*32 both fp16-normal; old 2^11 scale would subnormal-flush
//    61% of A weights): slot63=x_hi w/ Lg*W_ih; slot61=x_lo w/ /32.
//    xwriter packs slots 60..63 as one ds_write_b64 {0,xl,0,xh}.
// All else = R12/R15 (verified): NW=16, unit=4w+hi, hf[2][NB][72] fp16 h
// double-buffered, L-prescale, merged-rcp cell, guarded h-writes, ONE
// barrier/step. A row=lane&15 (gate=R&3, unit=4w+(R>>2)), k=8*hi+e
// (+32/K-step); B col=lane&15 same k; D col=lane&15 row=4*hi+reg.

#define BB 2048
#define TT 512
#define HH 50
#define NB 16            // batches per block (= MFMA cols)
#define NW 16            // waves = tiles; 64 unit slots (50 real)
#define XP 513           // xs row stride (floats)
#define HS 72            // hf unit-slot stride per batch row (u16; 144B)
#define XSC   32.0f      // x-lo scale (keeps both fp16 factors normal)
#define XSCI  0.03125f   // 1/32
#define L1 -1.4426950408889634f      // -log2(e)
#define L2 -2.8853900817779268f      // -2*log2(e)

typedef __attribute__((ext_vector_type(4))) float          f32x4;
typedef __attribute__((ext_vector_type(8))) _Float16       f16x8;
typedef __attribute__((ext_vector_type(4))) unsigned short u16x4;

__global__ __launch_bounds__(NW * 64)
void lstm_r16_kernel(const float* __restrict__ x,
                     const float* __restrict__ W_ih,
                     const float* __restrict__ W_hh,
                     const float* __restrict__ b_ih,
                     const float* __restrict__ b_hh,
                     const float* __restrict__ fc_w,
                     const float* __restrict__ fc_b,
                     float* __restrict__ out) {
    __shared__ float xs[NB * XP];                           // 32.8 KB
    __shared__ __align__(16) unsigned short hf[2][NB][HS];  // 4.6 KB (fp16 h + aug)
    __shared__ float hfin[NB][64];                          // 4 KB

    const int tid  = threadIdx.x;
    const int w    = tid >> 6;          // wave id = tile id, 0..15
    const int lane = tid & 63;
    const int hi   = lane >> 4;
    const int bcol = lane & 15;         // batch column
    const int b0   = blockIdx.x * NB;

    // ---- stage x rows (coalesced) + zero pad col 512 ----
    for (int idx = tid; idx < NB * TT; idx += NW * 64) {
        xs[(idx >> 9) * XP + (idx & 511)] = x[(b0 + (idx >> 9)) * TT + (idx & 511)];
    }
    if (tid < NB) xs[tid * XP + 512] = 0.0f;
    // ---- zero h state (both buffers incl. all pad/aug slots) ----
    for (int idx = tid; idx < (int)(sizeof(hf) / 4); idx += NW * 64) {
        ((unsigned*)hf)[idx] = 0;
    }

    // ---- A-fragments: permuted rows, L-prescaled single fp16 ----
    // Lane supplies A row R = lane&15: gate ga = R&3, unit ua = 4w+(R>>2).
    // k cols: [0,50) = fp16(Lg*W_hh); 61: fp16(Lg*W_ih/32) (pairs x_lo*32);
    // 63: fp16(Lg*W_ih) (pairs x_hi); rest 0. Bias moves to MFMA C.
    const int ga = bcol & 3;
    const int ua = 4 * w + (bcol >> 2);
    const bool ok = (ua < HH);
    const float Lg = (ga == 2) ? L2 : L1;
    f16x8 Ah0, Ah1;
    #pragma unroll
    for (int s = 0; s < 2; ++s) {
        #pragma unroll
        for (int e = 0; e < 8; ++e) {
            const int k = 32 * s + 8 * hi + e;
            _Float16 ah = (_Float16)0.0f;
            if (ok) {
                if (k < HH) {
                    ah = (_Float16)(Lg * W_hh[(ga * HH + ua) * HH + k]);   // RTN
                } else if (k == 61) {
                    ah = (_Float16)(Lg * W_ih[ga * HH + ua] * XSCI);
                } else if (k == 63) {
                    ah = (_Float16)(Lg * W_ih[ga * HH + ua]);
                }
            }
            if (s == 0) Ah0[e] = ah; else Ah1[e] = ah;
        }
    }

    // ---- bias as fp32 C-operand: reg r <-> gate r of unit 4w+hi ----
    f32x4 bias_c;
    #pragma unroll
    for (int r = 0; r < 4; ++r) {
        const int u = 4 * w + hi;
        const float Lr = (r == 2) ? L2 : L1;
        bias_c[r] = (u < HH) ? Lr * (b_ih[r * HH + u] + b_hh[r * HH + u]) : 0.0f;
    }

    // ---- LDS pointers (u16 units). buf stride = NB*HS = 1152 ----
    const unsigned short* rb  = &hf[0][bcol][8 * hi];    // B-frag reads
    unsigned short*       wb  = &hf[0][bcol][4 * w + hi];// h write (unit slot)
    unsigned short*       xwb = &hf[0][bcol][0];         // aug writes
    const bool xwriter = (w == 15) && (hi == 3);
    const bool hwriter = (4 * w + hi) < HH;   // pad units must not write

    __syncthreads();   // zero-init complete

    // ---- prologue aug write: x(0) -> buf0 slots 60..63 = {0,xl,0,xh} ----
    if (xwriter) {
        const float x0 = xs[bcol * XP + 0];
        const _Float16 xh = (_Float16)x0;
        const _Float16 xl = (_Float16)((x0 - (float)xh) * XSC);
        u16x4 P = {0, __builtin_bit_cast(unsigned short, xl), 0,
                      __builtin_bit_cast(unsigned short, xh)};
        *(u16x4*)(xwb + 60) = P;
    }

    float c = 0.0f, hcur = 0.0f;

    __syncthreads();

    // One step: read buf CB (h(t-1) + aug x(t)), write buf 1-CB, one barrier.
#define STEP(CB, T) { \
        const f16x8 B0 = *(const f16x8*)(rb + (CB) * 1152); \
        const f16x8 B1 = *(const f16x8*)(rb + (CB) * 1152 + 32); \
        f32x4 acc = __builtin_amdgcn_mfma_f32_16x16x32_f16(Ah0, B0, bias_c, 0, 0, 0); \
        acc = __builtin_amdgcn_mfma_f32_16x16x32_f16(Ah1, B1, acc, 0, 0, 0); \
        const float E1 = __builtin_amdgcn_exp2f(acc[0]);   /* i */ \
        const float E2 = __builtin_amdgcn_exp2f(acc[1]);   /* f */ \
        const float G  = __builtin_amdgcn_exp2f(acc[2]);   /* g */ \
        const float E4 = __builtin_amdgcn_exp2f(acc[3]);   /* o */ \
        const float P1 = 1.0f + E1, P2 = 1.0f + E2; \
        const float PG = 1.0f + G,  P4 = 1.0f + E4; \
        const float MG = 1.0f - G; \
        const float N  = fmaf(c * P1, PG, MG * P2); \
        const float D  = (P1 * P2) * PG; \
        c = N * __builtin_amdgcn_rcpf(D); \
        const float C5 = __builtin_amdgcn_exp2f(L2 * c); \
        const float Q  = (1.0f + C5) * P4; \
        hcur = (1.0f - C5) * __builtin_amdgcn_rcpf(Q); \
        if (hwriter) \
            wb[(1 - (CB)) * 1152] = __builtin_bit_cast(unsigned short, (_Float16)hcur); \
        if (xwriter) { \
            const float xn = xs[bcol * XP + (T) + 1]; \
            const _Float16 xh = (_Float16)xn; \
            const _Float16 xl = (_Float16)((xn - (float)xh) * XSC); \
            u16x4 P = {0, __builtin_bit_cast(unsigned short, xl), 0, \
                          __builtin_bit_cast(unsigned short, xh)}; \
            *(u16x4*)(xwb + (1 - (CB)) * 1152 + 60) = P; \
        } \
        __syncthreads(); }

    #pragma unroll 1
    for (int t = 0; t < TT; t += 2) {
        STEP(0, t)
        STEP(1, t + 1)
    }
#undef STEP

    // ---- epilogue: h_T dot fc_w (once) ----
    hfin[bcol][4 * w + hi] = hcur;      // pad units hold exact 0
    __syncthreads();
    if (tid < NB * 3) {
        const int b = tid / 3, o = tid % 3;
        float s = fc_b[o];
        for (int uu = 0; uu < HH; ++uu)
            s = fmaf(hfin[b][uu], fc_w[o * HH + uu], s);
        out[(b0 + b) * 3 + o] = s;
    }
}

extern "C" void kernel_launch(void* const* d_in, const int* in_sizes, int n_in,
                              void* d_out, int out_size, void* d_ws, size_t ws_size,
                              hipStream_t stream) {
    const float* x    = (const float*)d_in[0];
    const float* W_ih = (const float*)d_in[1];
    const float* W_hh = (const float*)d_in[2];
    const float* b_ih = (const float*)d_in[3];
    const float* b_hh = (const float*)d_in[4];
    const float* fc_w = (const float*)d_in[5];
    const float* fc_b = (const float*)d_in[6];
    float* out = (float*)d_out;

    dim3 grid(BB / NB);      // 128 blocks
    dim3 block(NW * 64);     // 1024 threads = 16 waves (4 per SIMD)
    lstm_r16_kernel<<<grid, block, 0, stream>>>(x, W_ih, W_hh, b_ih, b_hh,
                                                fc_w, fc_b, out);
}